// Round 16
// baseline (102.947 us; speedup 1.0000x reference)
//
#include <hip/hip_runtime.h>
#include <hip/hip_bf16.h>
#include <stdint.h>

#define E_ 8
#define H_ 1024
#define I_ 1024
#define T_ 8192
#define BM 128
#define BK 32
#define NKT 32

typedef __attribute__((ext_vector_type(4))) float f32x4;
typedef __attribute__((ext_vector_type(8))) short bf16x8;
typedef __attribute__((ext_vector_type(8))) unsigned short u16x8;

// HW RNE convert — compiler emits v_cvt_pk_bf16_f32 for adjacent pairs
__device__ __forceinline__ unsigned short f2bf_hw(float f) {
  __hip_bfloat16 h = __float2bfloat16(f);
  return __builtin_bit_cast(unsigned short, h);
}

__device__ __forceinline__ void gload_lds16(const void* g, void* l) {
  __builtin_amdgcn_global_load_lds(
      (const __attribute__((address_space(1))) unsigned int*)g,
      (__attribute__((address_space(3))) unsigned int*)l,
      16, 0, 0);
}

// ------------- expert lookup (tile height 128) -------------
__device__ __forceinline__ void find_tile(const int* counts, int ty,
                                          int& row_start, int& rows, int& expert) {
  int tacc = 0, off = 0;
  expert = 0; row_start = 0; rows = BM;
  #pragma unroll
  for (int e = 0; e < E_; ++e) {
    int c = counts[e];
    int te = (c + BM - 1) >> 7;
    if (ty >= tacc && ty < tacc + te) {
      expert = e;
      int lt = ty - tacc;
      row_start = off + lt * BM;
      rows = min(BM, c - lt * BM);
    }
    tacc += te; off += c;
  }
}

// =====================================================================
// preproc_w v4: 1024-thr blocks, 128 rows x 256 cols f32 in-tiles.
// Reads: 1 KB contiguous per row (4x page locality vs v3's 256 B).
// LDS [128][257] f32 = 131.6 KB (<=144 KB proven). Writes: 256 out-rows
// x 256 B segments (ushort8 per lane).
//   [0, 512)   : w1 [E][H][2I] -> [E][2I][H]   (8 bx x 8 by x 8 e)
//   [512, 768) : w2 [E][I][H]  -> [E][H][I]    (4 bx x 8 by x 8 e)
// =====================================================================
__device__ __forceinline__ void transpose_role4(const float* __restrict__ inp,
                                                unsigned short* __restrict__ outp,
                                                int R, int C, int bx, int by,
                                                float* tile /* [128*257] */) {
  int c0 = bx * 256, r0 = by * 128;
  int lcol = (threadIdx.x & 63) * 4;   // 64 float4 groups = 256 cols
  int lrow = threadIdx.x >> 6;         // 16 rows per pass
  #pragma unroll
  for (int p = 0; p < 8; ++p) {
    int r = p * 16 + lrow;
    float4 v = *reinterpret_cast<const float4*>(
        inp + (size_t)(r0 + r) * C + c0 + lcol);
    float* t = &tile[r * 257 + lcol];
    t[0] = v.x; t[1] = v.y; t[2] = v.z; t[3] = v.w;
  }
  __syncthreads();
  int lq = threadIdx.x & 15;           // r-chunk (8 f32) within out row
  int co = threadIdx.x >> 4;           // 64 out rows per pass
  #pragma unroll
  for (int p = 0; p < 4; ++p) {
    int cc = p * 64 + co;              // 256 out rows
    u16x8 o;
    #pragma unroll
    for (int i = 0; i < 8; ++i)
      o[i] = f2bf_hw(tile[(8 * lq + i) * 257 + cc]);
    *reinterpret_cast<u16x8*>(&outp[(size_t)(c0 + cc) * R + r0 + 8 * lq]) = o;
  }
}

__global__ __launch_bounds__(1024) void preproc_w(
    const float* __restrict__ w1, unsigned short* __restrict__ w1t,
    const float* __restrict__ w2, unsigned short* __restrict__ w2t) {
  __shared__ float tile[128 * 257];    // 131.6 KB
  int id = blockIdx.x;
  if (id < 512) {                      // w1: R=H_, C=2I
    int bx = id & 7, by = (id >> 3) & 7, bz = id >> 6;
    transpose_role4(w1 + (size_t)bz * H_ * 2 * I_,
                    w1t + (size_t)bz * H_ * 2 * I_, H_, 2 * I_, bx, by, tile);
    return;
  }
  int tb = id - 512;                   // w2: R=I_, C=H_
  int bx = tb & 3, by = (tb >> 2) & 7, bz = tb >> 5;
  transpose_role4(w2 + (size_t)bz * I_ * H_,
                  w2t + (size_t)bz * I_ * H_, I_, H_, bx, by, tile);
}

// =====================================================================
// GEMM1 + SwiGLU, fused x f32->bf16 (r15 proven, byte-identical):
// X32 [T][H] f32 x W1T [E][2I][H] bf16 -> Hout [T][I] bf16
// =====================================================================
#define GLDS (BM * BK + 256 * BK)           // shorts per ring buffer (24 KB)
__global__ __launch_bounds__(256, 2) void gemm1_swiglu(
    const float* __restrict__ X32,
    const unsigned short* __restrict__ W1T,
    const int* __restrict__ counts,
    unsigned short* __restrict__ Hout) {
  __shared__ unsigned short pool[3 * GLDS];  // 72 KB
  int id = blockIdx.x;
  int swz = (id & 7) * 64 + (id >> 3);      // 512 % 8 == 0, bijective
  int bn = swz & 7;                          // h block (128 wide)
  int tyid = swz >> 3;                       // M tile 0..63
  int row_start, rows, expert;
  find_tile(counts, tyid, row_start, rows, expert);
  int tid = threadIdx.x, wid = tid >> 6, lane = tid & 63;
  const unsigned short* Wp = W1T + (size_t)expert * (2 * I_) * H_;

  f32x4 acc[8][4];
  #pragma unroll
  for (int m = 0; m < 8; ++m)
    #pragma unroll
    for (int n = 0; n < 4; ++n) acc[m][n] = {0.f, 0.f, 0.f, 0.f};

  int l4 = lane >> 2;
  int csw = ((lane & 3) ^ ((l4 >> 1) & 3)) * 8;   // B pre-swizzled global k-chunk
  int lr = lane & 15;
  int ck = ((lane >> 4) ^ ((lr >> 1) & 3)) * 8;   // swizzled ds_read k-chunk

  int ar = tid >> 1;                 // row 0..127
  int ah = tid & 1;                  // k-half (16 floats)
  int agr = row_start + min(ar, rows - 1);
  const float* aptr = X32 + (size_t)agr * H_ + ah * 16;
  int asw = (ar >> 1) & 3;           // row swizzle
  int ap0 = ((2 * ah) ^ asw) * 8;
  int ap1 = ((2 * ah + 1) ^ asw) * 8;
  float4 aregA[4], aregB[4];

#define A_LOAD(kt, AR) do {                                                    \
    const float* p_ = aptr + (kt) * BK;                                        \
    AR[0] = *reinterpret_cast<const float4*>(p_);                              \
    AR[1] = *reinterpret_cast<const float4*>(p_ + 4);                          \
    AR[2] = *reinterpret_cast<const float4*>(p_ + 8);                          \
    AR[3] = *reinterpret_cast<const float4*>(p_ + 12);                         \
  } while (0)

#define A_WRITE(buf, AR) do {                                                  \
    unsigned short* Ab_ = pool + (buf) * GLDS;                                 \
    u16x8 o0, o1;                                                              \
    o0[0] = f2bf_hw(AR[0].x); o0[1] = f2bf_hw(AR[0].y);                        \
    o0[2] = f2bf_hw(AR[0].z); o0[3] = f2bf_hw(AR[0].w);                        \
    o0[4] = f2bf_hw(AR[1].x); o0[5] = f2bf_hw(AR[1].y);                        \
    o0[6] = f2bf_hw(AR[1].z); o0[7] = f2bf_hw(AR[1].w);                        \
    o1[0] = f2bf_hw(AR[2].x); o1[1] = f2bf_hw(AR[2].y);                        \
    o1[2] = f2bf_hw(AR[2].z); o1[3] = f2bf_hw(AR[2].w);                        \
    o1[4] = f2bf_hw(AR[3].x); o1[5] = f2bf_hw(AR[3].y);                        \
    o1[6] = f2bf_hw(AR[3].z); o1[7] = f2bf_hw(AR[3].w);                        \
    *reinterpret_cast<u16x8*>(&Ab_[ar * BK + ap0]) = o0;                       \
    *reinterpret_cast<u16x8*>(&Ab_[ar * BK + ap1]) = o1;                       \
  } while (0)

#define B_STAGE(buf, kt) do {                                                  \
    int k0 = (kt) * BK + csw;                                                  \
    unsigned short* Bb_ = pool + (buf) * GLDS + BM * BK;                       \
    _Pragma("unroll")                                                          \
    for (int i = 0; i < 4; ++i) {                                              \
      int r = wid * 64 + i * 16;                                               \
      int rb = r + l4;                                                         \
      int sub = rb & 63, ow = rb >> 6;                                         \
      int col = (sub < 32) ? (bn * 128 + ow * 32 + sub)                        \
                           : (I_ + bn * 128 + ow * 32 + sub - 32);             \
      gload_lds16(Wp + (size_t)col * H_ + k0, Bb_ + r * BK);                   \
    }                                                                          \
  } while (0)

#define CONSUME(kt) do {                                                       \
    const unsigned short* Ab = pool + ((kt) % 3) * GLDS;                       \
    const unsigned short* Bb = Ab + BM * BK;                                   \
    bf16x8 a[8], b[4];                                                         \
    _Pragma("unroll")                                                          \
    for (int m = 0; m < 8; ++m)                                                \
      a[m] = *reinterpret_cast<const bf16x8*>(&Ab[(m * 16 + lr) * BK + ck]);   \
    _Pragma("unroll")                                                          \
    for (int n = 0; n < 4; ++n)                                                \
      b[n] = *reinterpret_cast<const bf16x8*>(&Bb[(wid * 64 + n * 16 + lr) * BK + ck]); \
    __builtin_amdgcn_s_setprio(1);                                             \
    _Pragma("unroll")                                                          \
    for (int m = 0; m < 8; ++m)                                                \
      _Pragma("unroll")                                                        \
      for (int n = 0; n < 4; ++n)                                              \
        acc[m][n] = __builtin_amdgcn_mfma_f32_16x16x32_bf16(a[m], b[n], acc[m][n], 0, 0, 0); \
    __builtin_amdgcn_s_setprio(0);                                             \
    __builtin_amdgcn_s_barrier();                                              \
  } while (0)

#define ITER(kt, AR) do {                                                      \
    A_WRITE(((kt) + 1) % 3, AR);                                               \
    A_LOAD(min((kt) + 3, NKT - 1), AR);                                        \
    B_STAGE(((kt) + 2) % 3, min((kt) + 2, NKT - 1));                           \
    asm volatile("s_waitcnt vmcnt(8) lgkmcnt(0)" ::: "memory");                \
    __builtin_amdgcn_sched_barrier(0);                                         \
    __builtin_amdgcn_s_barrier();                                              \
    CONSUME(kt);                                                               \
  } while (0)

  A_LOAD(0, aregA);
  A_WRITE(0, aregA);
  A_LOAD(1, aregA);
  A_LOAD(2, aregB);
  B_STAGE(0, 0);
  B_STAGE(1, 1);
  asm volatile("s_waitcnt vmcnt(4) lgkmcnt(0)" ::: "memory");
  __builtin_amdgcn_sched_barrier(0);
  __builtin_amdgcn_s_barrier();

  for (int kt = 0; kt < NKT; kt += 2) {
    ITER(kt, aregA);
    ITER(kt + 1, aregB);
  }
#undef A_LOAD
#undef A_WRITE
#undef B_STAGE
#undef CONSUME
#undef ITER

  int lq = lane >> 4;
  #pragma unroll
  for (int m = 0; m < 8; ++m)
    #pragma unroll
    for (int n = 0; n < 2; ++n) {
      f32x4 g = acc[m][n], u = acc[m][n + 2];
      #pragma unroll
      for (int r = 0; r < 4; ++r) {
        int rl = m * 16 + lq * 4 + r;
        if (rl < rows) {
          float gv = g[r];
          float hv = (gv / (1.f + __expf(-gv))) * u[r];
          Hout[(size_t)(row_start + rl) * I_ + bn * 128 + wid * 32 + n * 16 + lr] = f2bf_hw(hv);
        }
      }
    }
}

// =====================================================================
// GEMM2 (r10/r12/r15 proven 8-phase): byte-identical.
// =====================================================================
#define GBUF 24576
#define GNKT 16

__device__ __forceinline__ bf16x8 ldfrag(const unsigned short* b, int row, int ck) {
  return *reinterpret_cast<const bf16x8*>(&b[row * 64 + ck]);
}

__global__ __launch_bounds__(512, 1) void gemm2(
    const unsigned short* __restrict__ Hin,
    const unsigned short* __restrict__ W2T,
    const int* __restrict__ counts,
    float* __restrict__ Out) {
  __shared__ unsigned short pool[3 * GBUF];   // 144 KB
  int id = blockIdx.x;
  int swz = (id & 7) * 32 + (id >> 3);        // 256 % 8 == 0
  int bn = swz & 3;
  int tyid = swz >> 2;
  int row_start, rows, expert;
  find_tile(counts, tyid, row_start, rows, expert);
  int tid = threadIdx.x, w = tid >> 6, lane = tid & 63;
  int wr = w >> 2, wc = w & 3;
  const unsigned short* Wp = W2T + (size_t)expert * H_ * I_;

  f32x4 acc[4][4];
  #pragma unroll
  for (int m = 0; m < 4; ++m)
    #pragma unroll
    for (int n = 0; n < 4; ++n) acc[m][n] = {0.f, 0.f, 0.f, 0.f};

  int lr = lane & 15, hi = lane >> 4;
  int ck0 = (hi ^ (lr & 7)) * 8;
  int ck1 = ((4 + hi) ^ (lr & 7)) * 8;
  int sr = lane >> 3;
  int cgo = ((lane & 7) ^ sr) * 8;

#define S2A(buf, kt, i) do {                                                   \
    int r = (w * 2 + (i)) * 8 + sr;                                            \
    int gr = row_start + min(r, rows - 1);                                     \
    gload_lds16(Hin + (size_t)gr * I_ + (kt) * 64 + cgo,                       \
                pool + (buf) * GBUF + (w * 2 + (i)) * 512);                    \
  } while (0)
#define S2B(buf, kt, i) do {                                                   \
    int rb = (w * 4 + (i)) * 8 + sr;                                           \
    int col = bn * 256 + rb;                                                   \
    gload_lds16(Wp + (size_t)col * I_ + (kt) * 64 + cgo,                       \
                pool + (buf) * GBUF + 8192 + (w * 4 + (i)) * 512);             \
  } while (0)

  S2A(0, 0, 0); S2A(0, 0, 1); S2B(0, 0, 0); S2B(0, 0, 1); S2B(0, 0, 2); S2B(0, 0, 3);
  S2A(1, 1, 0); S2A(1, 1, 1); S2B(1, 1, 0); S2B(1, 1, 1); S2B(1, 1, 2); S2B(1, 1, 3);
  asm volatile("s_waitcnt vmcnt(6)" ::: "memory");
  __builtin_amdgcn_sched_barrier(0);
  __builtin_amdgcn_s_barrier();

  for (int t = 0; t < GNKT; ++t) {
    const unsigned short* Ab = pool + (t % 3) * GBUF;
    const unsigned short* Bb = Ab + 8192;
    int dst = (t + 2) % 3;
    int nk = t + 2;
    bool pre = (nk < GNKT);
    bf16x8 bf[4], af[2];
    // phase 0
    #pragma unroll
    for (int n = 0; n < 4; ++n) bf[n] = ldfrag(Bb, wc * 64 + n * 16 + lr, ck0);
    af[0] = ldfrag(Ab, wr * 64 + lr, ck0);
    af[1] = ldfrag(Ab, wr * 64 + 16 + lr, ck0);
    if (pre) S2A(dst, nk, 0);
    __builtin_amdgcn_s_barrier();
    __builtin_amdgcn_s_setprio(1);
    #pragma unroll
    for (int m = 0; m < 2; ++m)
      #pragma unroll
      for (int n = 0; n < 4; ++n)
        acc[m][n] = __builtin_amdgcn_mfma_f32_16x16x32_bf16(af[m], bf[n], acc[m][n], 0, 0, 0);
    __builtin_amdgcn_s_setprio(0);
    __builtin_amdgcn_s_barrier();
    // phase 1
    af[0] = ldfrag(Ab, wr * 64 + 32 + lr, ck0);
    af[1] = ldfrag(Ab, wr * 64 + 48 + lr, ck0);
    if (pre) S2A(dst, nk, 1);
    __builtin_amdgcn_s_barrier();
    __builtin_amdgcn_s_setprio(1);
    #pragma unroll
    for (int m = 0; m < 2; ++m)
      #pragma unroll
      for (int n = 0; n < 4; ++n)
        acc[m + 2][n] = __builtin_amdgcn_mfma_f32_16x16x32_bf16(af[m], bf[n], acc[m + 2][n], 0, 0, 0);
    __builtin_amdgcn_s_setprio(0);
    __builtin_amdgcn_s_barrier();
    // phase 2
    #pragma unroll
    for (int n = 0; n < 4; ++n) bf[n] = ldfrag(Bb, wc * 64 + n * 16 + lr, ck1);
    af[0] = ldfrag(Ab, wr * 64 + lr, ck1);
    af[1] = ldfrag(Ab, wr * 64 + 16 + lr, ck1);
    if (pre) { S2B(dst, nk, 0); S2B(dst, nk, 1); }
    __builtin_amdgcn_s_barrier();
    __builtin_amdgcn_s_setprio(1);
    #pragma unroll
    for (int m = 0; m < 2; ++m)
      #pragma unroll
      for (int n = 0; n < 4; ++n)
        acc[m][n] = __builtin_amdgcn_mfma_f32_16x16x32_bf16(af[m], bf[n], acc[m][n], 0, 0, 0);
    __builtin_amdgcn_s_setprio(0);
    __builtin_amdgcn_s_barrier();
    // phase 3 (+ vmcnt guard)
    af[0] = ldfrag(Ab, wr * 64 + 32 + lr, ck1);
    af[1] = ldfrag(Ab, wr * 64 + 48 + lr, ck1);
    if (pre) {
      S2B(dst, nk, 2); S2B(dst, nk, 3);
      asm volatile("s_waitcnt vmcnt(6)" ::: "memory");
    } else {
      asm volatile("s_waitcnt vmcnt(0)" ::: "memory");
    }
    __builtin_amdgcn_sched_barrier(0);
    __builtin_amdgcn_s_barrier();
    __builtin_amdgcn_s_setprio(1);
    #pragma unroll
    for (int m = 0; m < 2; ++m)
      #pragma unroll
      for (int n = 0; n < 4; ++n)
        acc[m + 2][n] = __builtin_amdgcn_mfma_f32_16x16x32_bf16(af[m], bf[n], acc[m + 2][n], 0, 0, 0);
    __builtin_amdgcn_s_setprio(0);
    __builtin_amdgcn_s_barrier();
  }
#undef S2A
#undef S2B

  int lq = lane >> 4;
  #pragma unroll
  for (int m = 0; m < 4; ++m)
    #pragma unroll
    for (int n = 0; n < 4; ++n)
      #pragma unroll
      for (int r = 0; r < 4; ++r) {
        int rl = wr * 64 + m * 16 + lq * 4 + r;
        if (rl < rows)
          Out[(size_t)(row_start + rl) * H_ + bn * 256 + wc * 64 + n * 16 + lr] =
              acc[m][n][r];
      }
}

extern "C" void kernel_launch(void* const* d_in, const int* in_sizes, int n_in,
                              void* d_out, int out_size, void* d_ws, size_t ws_size,
                              hipStream_t stream) {
  const float* x  = (const float*)d_in[0];
  const float* w1 = (const float*)d_in[1];   // [E][H][2I]
  const float* w2 = (const float*)d_in[2];   // [E][I][H]
  const int* counts = (const int*)d_in[3];
  float* out = (float*)d_out;

  char* ws = (char*)d_ws;
  unsigned short* w1t = (unsigned short*)ws;
  unsigned short* w2t = (unsigned short*)(ws + (size_t)E_ * 2 * I_ * H_ * 2);
  unsigned short* hbuf = (unsigned short*)(ws + (size_t)E_ * 2 * I_ * H_ * 2
                                              + (size_t)E_ * H_ * I_ * 2);

  // 1) weight transposes (v4: 128x256 tiles, 1 KB-contiguous reads)
  preproc_w<<<768, 1024, 0, stream>>>(w1, w1t, w2, w2t);
  // 2) grouped GEMM1 + SwiGLU, fused x convert (r15 proven)
  gemm1_swiglu<<<512, 256, 0, stream>>>(x, w1t, counts, hbuf);
  // 3) grouped GEMM2 (8-phase)
  gemm2<<<256, 512, 0, stream>>>(hbuf, w2t, counts, out);
}

// Round 17
// 98.669 us; speedup vs baseline: 1.0434x; 1.0434x over previous
//
#include <hip/hip_runtime.h>
#include <hip/hip_bf16.h>
#include <stdint.h>

#define E_ 8
#define H_ 1024
#define I_ 1024
#define T_ 8192
#define BM 128
#define BK 32
#define NKT 32

typedef __attribute__((ext_vector_type(4))) float f32x4;
typedef __attribute__((ext_vector_type(8))) short bf16x8;
typedef __attribute__((ext_vector_type(8))) unsigned short u16x8;

// HW RNE convert — compiler emits v_cvt_pk_bf16_f32 for adjacent pairs
__device__ __forceinline__ unsigned short f2bf_hw(float f) {
  __hip_bfloat16 h = __float2bfloat16(f);
  return __builtin_bit_cast(unsigned short, h);
}

__device__ __forceinline__ void gload_lds16(const void* g, void* l) {
  __builtin_amdgcn_global_load_lds(
      (const __attribute__((address_space(1))) unsigned int*)g,
      (__attribute__((address_space(3))) unsigned int*)l,
      16, 0, 0);
}

// ------------- expert lookup (tile height 128) -------------
__device__ __forceinline__ void find_tile(const int* counts, int ty,
                                          int& row_start, int& rows, int& expert) {
  int tacc = 0, off = 0;
  expert = 0; row_start = 0; rows = BM;
  #pragma unroll
  for (int e = 0; e < E_; ++e) {
    int c = counts[e];
    int te = (c + BM - 1) >> 7;
    if (ty >= tacc && ty < tacc + te) {
      expert = e;
      int lt = ty - tacc;
      row_start = off + lt * BM;
      rows = min(BM, c - lt * BM);
    }
    tacc += te; off += c;
  }
}

// ---------- transpose role v3 (r12/r15 proven): 16 B loads / 16 B stores ----------
__device__ __forceinline__ void transpose_role(const float* __restrict__ inp,
                                               unsigned short* __restrict__ outp,
                                               int R, int C, int bx, int by,
                                               float* tile /* [128*65] */) {
  int c0 = bx * 64, r0 = by * 128;
  int lc = threadIdx.x & 15;
  int lrw = threadIdx.x >> 4;
  #pragma unroll
  for (int p = 0; p < 8; ++p) {
    int r = p * 16 + lrw;
    float4 v = *reinterpret_cast<const float4*>(
        inp + (size_t)(r0 + r) * C + c0 + lc * 4);
    float* t = &tile[r * 65 + lc * 4];
    t[0] = v.x; t[1] = v.y; t[2] = v.z; t[3] = v.w;
  }
  __syncthreads();
  int lq = threadIdx.x & 15;
  int co = threadIdx.x >> 4;
  #pragma unroll
  for (int p = 0; p < 4; ++p) {
    int cc = p * 16 + co;
    u16x8 o;
    #pragma unroll
    for (int i = 0; i < 8; ++i)
      o[i] = f2bf_hw(tile[(8 * lq + i) * 65 + cc]);
    *reinterpret_cast<u16x8*>(&outp[(size_t)(c0 + cc) * R + r0 + 8 * lq]) = o;
  }
}

// =====================================================================
// preproc_w (r15 proven): weights only.
//   [0, 2048)    : transpose+convert w1 [E][H][2I] -> [E][2I][H]
//   [2048, 3072) : transpose+convert w2 [E][I][H]  -> [E][H][I]
// =====================================================================
__global__ __launch_bounds__(256) void preproc_w(
    const float* __restrict__ w1, unsigned short* __restrict__ w1t,
    const float* __restrict__ w2, unsigned short* __restrict__ w2t) {
  __shared__ float tile[128 * 65];
  int id = blockIdx.x;
  if (id < 2048) {                          // w1: R=H_, C=2I -> 32 x 8 x 8
    int bx = id & 31, by = (id >> 5) & 7, bz = id >> 8;
    transpose_role(w1 + (size_t)bz * H_ * 2 * I_,
                   w1t + (size_t)bz * H_ * 2 * I_, H_, 2 * I_, bx, by, tile);
    return;
  }
  int tb = id - 2048;                       // w2: R=I_, C=H_ -> 16 x 8 x 8
  int bx = tb & 15, by = (tb >> 4) & 7, bz = tb >> 7;
  transpose_role(w2 + (size_t)bz * I_ * H_,
                 w2t + (size_t)bz * I_ * H_, I_, H_, bx, by, tile);
}

// =====================================================================
// GEMM1 + SwiGLU, fused x f32->bf16 (r15 proven, byte-identical):
// X32 [T][H] f32 x W1T [E][2I][H] bf16 -> Hout [T][I] bf16
// Schedule: single-wait, double areg:
//   A_WRITE(t+1) -> A_LOAD(t+3) -> B_STAGE(t+2) -> vmcnt(8)+lgkmcnt(0)
//   -> barrier -> consume(t) -> barrier.
// grid 512 = 8 bn x 64 ty, XCD-swizzled.
// =====================================================================
#define GLDS (BM * BK + 256 * BK)           // shorts per ring buffer (24 KB)
__global__ __launch_bounds__(256, 2) void gemm1_swiglu(
    const float* __restrict__ X32,
    const unsigned short* __restrict__ W1T,
    const int* __restrict__ counts,
    unsigned short* __restrict__ Hout) {
  __shared__ unsigned short pool[3 * GLDS];  // 72 KB
  int id = blockIdx.x;
  int swz = (id & 7) * 64 + (id >> 3);      // 512 % 8 == 0, bijective
  int bn = swz & 7;                          // h block (128 wide)
  int tyid = swz >> 3;                       // M tile 0..63
  int row_start, rows, expert;
  find_tile(counts, tyid, row_start, rows, expert);
  int tid = threadIdx.x, wid = tid >> 6, lane = tid & 63;
  const unsigned short* Wp = W1T + (size_t)expert * (2 * I_) * H_;

  f32x4 acc[8][4];
  #pragma unroll
  for (int m = 0; m < 8; ++m)
    #pragma unroll
    for (int n = 0; n < 4; ++n) acc[m][n] = {0.f, 0.f, 0.f, 0.f};

  int l4 = lane >> 2;
  int csw = ((lane & 3) ^ ((l4 >> 1) & 3)) * 8;   // B pre-swizzled global k-chunk
  int lr = lane & 15;
  int ck = ((lane >> 4) ^ ((lr >> 1) & 3)) * 8;   // swizzled ds_read k-chunk

  int ar = tid >> 1;                 // row 0..127
  int ah = tid & 1;                  // k-half (16 floats)
  int agr = row_start + min(ar, rows - 1);
  const float* aptr = X32 + (size_t)agr * H_ + ah * 16;
  int asw = (ar >> 1) & 3;           // row swizzle
  int ap0 = ((2 * ah) ^ asw) * 8;
  int ap1 = ((2 * ah + 1) ^ asw) * 8;
  float4 aregA[4], aregB[4];

#define A_LOAD(kt, AR) do {                                                    \
    const float* p_ = aptr + (kt) * BK;                                        \
    AR[0] = *reinterpret_cast<const float4*>(p_);                              \
    AR[1] = *reinterpret_cast<const float4*>(p_ + 4);                          \
    AR[2] = *reinterpret_cast<const float4*>(p_ + 8);                          \
    AR[3] = *reinterpret_cast<const float4*>(p_ + 12);                         \
  } while (0)

#define A_WRITE(buf, AR) do {                                                  \
    unsigned short* Ab_ = pool + (buf) * GLDS;                                 \
    u16x8 o0, o1;                                                              \
    o0[0] = f2bf_hw(AR[0].x); o0[1] = f2bf_hw(AR[0].y);                        \
    o0[2] = f2bf_hw(AR[0].z); o0[3] = f2bf_hw(AR[0].w);                        \
    o0[4] = f2bf_hw(AR[1].x); o0[5] = f2bf_hw(AR[1].y);                        \
    o0[6] = f2bf_hw(AR[1].z); o0[7] = f2bf_hw(AR[1].w);                        \
    o1[0] = f2bf_hw(AR[2].x); o1[1] = f2bf_hw(AR[2].y);                        \
    o1[2] = f2bf_hw(AR[2].z); o1[3] = f2bf_hw(AR[2].w);                        \
    o1[4] = f2bf_hw(AR[3].x); o1[5] = f2bf_hw(AR[3].y);                        \
    o1[6] = f2bf_hw(AR[3].z); o1[7] = f2bf_hw(AR[3].w);                        \
    *reinterpret_cast<u16x8*>(&Ab_[ar * BK + ap0]) = o0;                       \
    *reinterpret_cast<u16x8*>(&Ab_[ar * BK + ap1]) = o1;                       \
  } while (0)

#define B_STAGE(buf, kt) do {                                                  \
    int k0 = (kt) * BK + csw;                                                  \
    unsigned short* Bb_ = pool + (buf) * GLDS + BM * BK;                       \
    _Pragma("unroll")                                                          \
    for (int i = 0; i < 4; ++i) {                                              \
      int r = wid * 64 + i * 16;                                               \
      int rb = r + l4;                                                         \
      int sub = rb & 63, ow = rb >> 6;                                         \
      int col = (sub < 32) ? (bn * 128 + ow * 32 + sub)                        \
                           : (I_ + bn * 128 + ow * 32 + sub - 32);             \
      gload_lds16(Wp + (size_t)col * H_ + k0, Bb_ + r * BK);                   \
    }                                                                          \
  } while (0)

#define CONSUME(kt) do {                                                       \
    const unsigned short* Ab = pool + ((kt) % 3) * GLDS;                       \
    const unsigned short* Bb = Ab + BM * BK;                                   \
    bf16x8 a[8], b[4];                                                         \
    _Pragma("unroll")                                                          \
    for (int m = 0; m < 8; ++m)                                                \
      a[m] = *reinterpret_cast<const bf16x8*>(&Ab[(m * 16 + lr) * BK + ck]);   \
    _Pragma("unroll")                                                          \
    for (int n = 0; n < 4; ++n)                                                \
      b[n] = *reinterpret_cast<const bf16x8*>(&Bb[(wid * 64 + n * 16 + lr) * BK + ck]); \
    __builtin_amdgcn_s_setprio(1);                                             \
    _Pragma("unroll")                                                          \
    for (int m = 0; m < 8; ++m)                                                \
      _Pragma("unroll")                                                        \
      for (int n = 0; n < 4; ++n)                                              \
        acc[m][n] = __builtin_amdgcn_mfma_f32_16x16x32_bf16(a[m], b[n], acc[m][n], 0, 0, 0); \
    __builtin_amdgcn_s_setprio(0);                                             \
    __builtin_amdgcn_s_barrier();                                              \
  } while (0)

#define ITER(kt, AR) do {                                                      \
    A_WRITE(((kt) + 1) % 3, AR);                                               \
    A_LOAD(min((kt) + 3, NKT - 1), AR);                                        \
    B_STAGE(((kt) + 2) % 3, min((kt) + 2, NKT - 1));                           \
    asm volatile("s_waitcnt vmcnt(8) lgkmcnt(0)" ::: "memory");                \
    __builtin_amdgcn_sched_barrier(0);                                         \
    __builtin_amdgcn_s_barrier();                                              \
    CONSUME(kt);                                                               \
  } while (0)

  A_LOAD(0, aregA);
  A_WRITE(0, aregA);
  A_LOAD(1, aregA);
  A_LOAD(2, aregB);
  B_STAGE(0, 0);
  B_STAGE(1, 1);
  asm volatile("s_waitcnt vmcnt(4) lgkmcnt(0)" ::: "memory");
  __builtin_amdgcn_sched_barrier(0);
  __builtin_amdgcn_s_barrier();

  for (int kt = 0; kt < NKT; kt += 2) {
    ITER(kt, aregA);
    ITER(kt + 1, aregB);
  }
#undef A_LOAD
#undef A_WRITE
#undef B_STAGE
#undef CONSUME
#undef ITER

  int lq = lane >> 4;
  #pragma unroll
  for (int m = 0; m < 8; ++m)
    #pragma unroll
    for (int n = 0; n < 2; ++n) {
      f32x4 g = acc[m][n], u = acc[m][n + 2];
      #pragma unroll
      for (int r = 0; r < 4; ++r) {
        int rl = m * 16 + lq * 4 + r;
        if (rl < rows) {
          float gv = g[r];
          float hv = (gv / (1.f + __expf(-gv))) * u[r];
          Hout[(size_t)(row_start + rl) * I_ + bn * 128 + wid * 32 + n * 16 + lr] = f2bf_hw(hv);
        }
      }
    }
}

// =====================================================================
// GEMM2 (r10/r12/r15 proven 8-phase): byte-identical.
// =====================================================================
#define GBUF 24576
#define GNKT 16

__device__ __forceinline__ bf16x8 ldfrag(const unsigned short* b, int row, int ck) {
  return *reinterpret_cast<const bf16x8*>(&b[row * 64 + ck]);
}

__global__ __launch_bounds__(512, 1) void gemm2(
    const unsigned short* __restrict__ Hin,
    const unsigned short* __restrict__ W2T,
    const int* __restrict__ counts,
    float* __restrict__ Out) {
  __shared__ unsigned short pool[3 * GBUF];   // 144 KB
  int id = blockIdx.x;
  int swz = (id & 7) * 32 + (id >> 3);        // 256 % 8 == 0
  int bn = swz & 3;
  int tyid = swz >> 2;
  int row_start, rows, expert;
  find_tile(counts, tyid, row_start, rows, expert);
  int tid = threadIdx.x, w = tid >> 6, lane = tid & 63;
  int wr = w >> 2, wc = w & 3;
  const unsigned short* Wp = W2T + (size_t)expert * H_ * I_;

  f32x4 acc[4][4];
  #pragma unroll
  for (int m = 0; m < 4; ++m)
    #pragma unroll
    for (int n = 0; n < 4; ++n) acc[m][n] = {0.f, 0.f, 0.f, 0.f};

  int lr = lane & 15, hi = lane >> 4;
  int ck0 = (hi ^ (lr & 7)) * 8;
  int ck1 = ((4 + hi) ^ (lr & 7)) * 8;
  int sr = lane >> 3;
  int cgo = ((lane & 7) ^ sr) * 8;

#define S2A(buf, kt, i) do {                                                   \
    int r = (w * 2 + (i)) * 8 + sr;                                            \
    int gr = row_start + min(r, rows - 1);                                     \
    gload_lds16(Hin + (size_t)gr * I_ + (kt) * 64 + cgo,                       \
                pool + (buf) * GBUF + (w * 2 + (i)) * 512);                    \
  } while (0)
#define S2B(buf, kt, i) do {                                                   \
    int rb = (w * 4 + (i)) * 8 + sr;                                           \
    int col = bn * 256 + rb;                                                   \
    gload_lds16(Wp + (size_t)col * I_ + (kt) * 64 + cgo,                       \
                pool + (buf) * GBUF + 8192 + (w * 4 + (i)) * 512);             \
  } while (0)

  S2A(0, 0, 0); S2A(0, 0, 1); S2B(0, 0, 0); S2B(0, 0, 1); S2B(0, 0, 2); S2B(0, 0, 3);
  S2A(1, 1, 0); S2A(1, 1, 1); S2B(1, 1, 0); S2B(1, 1, 1); S2B(1, 1, 2); S2B(1, 1, 3);
  asm volatile("s_waitcnt vmcnt(6)" ::: "memory");
  __builtin_amdgcn_sched_barrier(0);
  __builtin_amdgcn_s_barrier();

  for (int t = 0; t < GNKT; ++t) {
    const unsigned short* Ab = pool + (t % 3) * GBUF;
    const unsigned short* Bb = Ab + 8192;
    int dst = (t + 2) % 3;
    int nk = t + 2;
    bool pre = (nk < GNKT);
    bf16x8 bf[4], af[2];
    // phase 0
    #pragma unroll
    for (int n = 0; n < 4; ++n) bf[n] = ldfrag(Bb, wc * 64 + n * 16 + lr, ck0);
    af[0] = ldfrag(Ab, wr * 64 + lr, ck0);
    af[1] = ldfrag(Ab, wr * 64 + 16 + lr, ck0);
    if (pre) S2A(dst, nk, 0);
    __builtin_amdgcn_s_barrier();
    __builtin_amdgcn_s_setprio(1);
    #pragma unroll
    for (int m = 0; m < 2; ++m)
      #pragma unroll
      for (int n = 0; n < 4; ++n)
        acc[m][n] = __builtin_amdgcn_mfma_f32_16x16x32_bf16(af[m], bf[n], acc[m][n], 0, 0, 0);
    __builtin_amdgcn_s_setprio(0);
    __builtin_amdgcn_s_barrier();
    // phase 1
    af[0] = ldfrag(Ab, wr * 64 + 32 + lr, ck0);
    af[1] = ldfrag(Ab, wr * 64 + 48 + lr, ck0);
    if (pre) S2A(dst, nk, 1);
    __builtin_amdgcn_s_barrier();
    __builtin_amdgcn_s_setprio(1);
    #pragma unroll
    for (int m = 0; m < 2; ++m)
      #pragma unroll
      for (int n = 0; n < 4; ++n)
        acc[m + 2][n] = __builtin_amdgcn_mfma_f32_16x16x32_bf16(af[m], bf[n], acc[m + 2][n], 0, 0, 0);
    __builtin_amdgcn_s_setprio(0);
    __builtin_amdgcn_s_barrier();
    // phase 2
    #pragma unroll
    for (int n = 0; n < 4; ++n) bf[n] = ldfrag(Bb, wc * 64 + n * 16 + lr, ck1);
    af[0] = ldfrag(Ab, wr * 64 + lr, ck1);
    af[1] = ldfrag(Ab, wr * 64 + 16 + lr, ck1);
    if (pre) { S2B(dst, nk, 0); S2B(dst, nk, 1); }
    __builtin_amdgcn_s_barrier();
    __builtin_amdgcn_s_setprio(1);
    #pragma unroll
    for (int m = 0; m < 2; ++m)
      #pragma unroll
      for (int n = 0; n < 4; ++n)
        acc[m][n] = __builtin_amdgcn_mfma_f32_16x16x32_bf16(af[m], bf[n], acc[m][n], 0, 0, 0);
    __builtin_amdgcn_s_setprio(0);
    __builtin_amdgcn_s_barrier();
    // phase 3 (+ vmcnt guard)
    af[0] = ldfrag(Ab, wr * 64 + 32 + lr, ck1);
    af[1] = ldfrag(Ab, wr * 64 + 48 + lr, ck1);
    if (pre) {
      S2B(dst, nk, 2); S2B(dst, nk, 3);
      asm volatile("s_waitcnt vmcnt(6)" ::: "memory");
    } else {
      asm volatile("s_waitcnt vmcnt(0)" ::: "memory");
    }
    __builtin_amdgcn_sched_barrier(0);
    __builtin_amdgcn_s_barrier();
    __builtin_amdgcn_s_setprio(1);
    #pragma unroll
    for (int m = 0; m < 2; ++m)
      #pragma unroll
      for (int n = 0; n < 4; ++n)
        acc[m + 2][n] = __builtin_amdgcn_mfma_f32_16x16x32_bf16(af[m], bf[n], acc[m + 2][n], 0, 0, 0);
    __builtin_amdgcn_s_setprio(0);
    __builtin_amdgcn_s_barrier();
  }
#undef S2A
#undef S2B

  int lq = lane >> 4;
  #pragma unroll
  for (int m = 0; m < 4; ++m)
    #pragma unroll
    for (int n = 0; n < 4; ++n)
      #pragma unroll
      for (int r = 0; r < 4; ++r) {
        int rl = wr * 64 + m * 16 + lq * 4 + r;
        if (rl < rows)
          Out[(size_t)(row_start + rl) * H_ + bn * 256 + wc * 64 + n * 16 + lr] =
              acc[m][n][r];
      }
}

extern "C" void kernel_launch(void* const* d_in, const int* in_sizes, int n_in,
                              void* d_out, int out_size, void* d_ws, size_t ws_size,
                              hipStream_t stream) {
  const float* x  = (const float*)d_in[0];
  const float* w1 = (const float*)d_in[1];   // [E][H][2I]
  const float* w2 = (const float*)d_in[2];   // [E][I][H]
  const int* counts = (const int*)d_in[3];
  float* out = (float*)d_out;

  char* ws = (char*)d_ws;
  unsigned short* w1t = (unsigned short*)ws;
  unsigned short* w2t = (unsigned short*)(ws + (size_t)E_ * 2 * I_ * H_ * 2);
  unsigned short* hbuf = (unsigned short*)(ws + (size_t)E_ * 2 * I_ * H_ * 2
                                              + (size_t)E_ * H_ * I_ * 2);

  // 1) weight transposes (v3 — best measured)
  preproc_w<<<3072, 256, 0, stream>>>(w1, w1t, w2, w2t);
  // 2) grouped GEMM1 + SwiGLU, fused x convert (HW cvt_pk)
  gemm1_swiglu<<<512, 256, 0, stream>>>(x, w1t, counts, hbuf);
  // 3) grouped GEMM2 (8-phase)
  gemm2<<<256, 512, 0, stream>>>(hbuf, w2t, counts, out);
}